// Round 1
// baseline (455.216 us; speedup 1.0000x reference)
//
#include <hip/hip_runtime.h>
#include <hip/hip_bf16.h>
#include <math.h>

// Problem constants
#define T_TOK   32768            // B*S tokens
#define EDIM    768
#define FDIM    3072
#define NQ      8

// Tiling
#define BM      128
#define BN      128
#define BK      64
#define NPANEL  (EDIM / BN)      // 6
#define NMBLK   (T_TOK / BM)     // 256
#define NKSTEP  (FDIM / BK)      // 48

// LDS padded strides (bf16 elements). 72*2=144B row stride breaks the
// 128B-stride 16-way bank conflict on ds_read_b128 (bank rotates by 4/row).
#define HA_ST   72
#define BT_ST   72

typedef float f32x4  __attribute__((ext_vector_type(4)));
typedef short bf16x8 __attribute__((ext_vector_type(8)));

// f32 -> bf16 bits, round-to-nearest-even (explicit: truncation bias over
// K=3072 accumulation would approach the 0.0386 absmax threshold).
static __device__ __forceinline__ unsigned short f2bf(float f) {
    unsigned int u = __float_as_uint(f);
    unsigned int r = (u + 0x7FFFu + ((u >> 16) & 1u)) >> 16;
    return (unsigned short)r;
}

__global__ __launch_bounds__(256) void ffq_fused(
    const float* __restrict__ x,
    const float* __restrict__ theta,
    const float* __restrict__ W1,
    const float* __restrict__ W2,
    float* __restrict__ out)
{
    __shared__ __align__(16) unsigned short hA[BM * HA_ST];  // h tile, bf16 bits
    __shared__ __align__(16) unsigned short Bt[BN * BT_ST];  // W2 tile, bf16 bits

    const int tid  = threadIdx.x;
    const int wave = tid >> 6;          // 0..3
    const int lane = tid & 63;
    const int l15  = lane & 15;
    const int lhi  = lane >> 4;         // 0..3
    const int wm   = wave >> 1;         // 0..1 (M direction)
    const int wn   = wave & 1;          // 0..1 (N direction)

    const int panel = blockIdx.x / NMBLK;   // 0..5  (same-panel blocks adjacent -> B locality)
    const int mblk  = blockIdx.x % NMBLK;   // 0..255
    const int t0 = mblk * BM;
    const int n0 = panel * BN;

    // ---- Hoisted Z fragments (A operand of the expansion MFMA) ----
    // Expansion GEMM per k-step: h[128,64] = Z[128, K=32(pad)] @ W1T[32, 64].
    // A-frag layout (16x16x32): row = lane&15, k = (lane>>4)*8 + j.
    // Only lanes 0..15 carry real k=0..7; lanes 16..63 hold the K zero-padding.
    // Wave handles h-row slabs s=0,1: rows (wave*2+s)*16 .. +15.
    bf16x8 zf[2];
    #pragma unroll
    for (int s = 0; s < 2; ++s) {
        bf16x8 z = {0, 0, 0, 0, 0, 0, 0, 0};
        if (lhi == 0) {
            const int tok = t0 + (wave * 2 + s) * 16 + l15;
            const float4* xp = (const float4*)(x + (size_t)tok * EDIM);
            const float4 x0 = xp[0];
            const float4 x1 = xp[1];
            z[0] = (short)f2bf(cosf(x0.x) * cosf(theta[0]));
            z[1] = (short)f2bf(cosf(x0.y) * cosf(theta[1]));
            z[2] = (short)f2bf(cosf(x0.z) * cosf(theta[2]));
            z[3] = (short)f2bf(cosf(x0.w) * cosf(theta[3]));
            z[4] = (short)f2bf(cosf(x1.x) * cosf(theta[4]));
            z[5] = (short)f2bf(cosf(x1.y) * cosf(theta[5]));
            z[6] = (short)f2bf(cosf(x1.z) * cosf(theta[6]));
            z[7] = (short)f2bf(cosf(x1.w) * cosf(theta[7]));
        }
        zf[s] = z;
    }

    f32x4 acc[4][4];
    #pragma unroll
    for (int mi = 0; mi < 4; ++mi)
        #pragma unroll
        for (int ni = 0; ni < 4; ++ni)
            acc[mi][ni] = (f32x4){0.f, 0.f, 0.f, 0.f};

    for (int ks = 0; ks < NKSTEP; ++ks) {
        const int k0 = ks * BK;

        __syncthreads();   // previous iteration's LDS reads complete

        // ---- Stage Bt: W2[n0+e][k0..k0+63] -> bf16 LDS ----
        {
            const int e    = tid >> 1;           // 0..127
            const int half = (tid & 1) * 32;     // 0 or 32
            const float* src = W2 + (size_t)(n0 + e) * FDIM + k0 + half;
            unsigned short* dst = &Bt[e * BT_ST + half];
            #pragma unroll
            for (int i = 0; i < 4; ++i) {
                const float4 a = ((const float4*)src)[2 * i];
                const float4 b = ((const float4*)src)[2 * i + 1];
                bf16x8 v;
                v[0] = (short)f2bf(a.x); v[1] = (short)f2bf(a.y);
                v[2] = (short)f2bf(a.z); v[3] = (short)f2bf(a.w);
                v[4] = (short)f2bf(b.x); v[5] = (short)f2bf(b.y);
                v[6] = (short)f2bf(b.z); v[7] = (short)f2bf(b.w);
                *(bf16x8*)(dst + i * 8) = v;
            }
        }

        // ---- Expansion: h[128, 64] = relu(Z @ W1T), written to hA ----
        // B-frag (16x16x32): col = lane&15, k = (lane>>4)*8 + j; only lanes
        // 0..15 carry real k (q=0..7), rest are zero-padding.
        #pragma unroll
        for (int ns = 0; ns < 4; ++ns) {
            bf16x8 wf = {0, 0, 0, 0, 0, 0, 0, 0};
            if (lhi == 0) {
                const float* wp = W1 + (size_t)(k0 + ns * 16 + l15) * NQ;
                const float4 a = ((const float4*)wp)[0];
                const float4 b = ((const float4*)wp)[1];
                wf[0] = (short)f2bf(a.x); wf[1] = (short)f2bf(a.y);
                wf[2] = (short)f2bf(a.z); wf[3] = (short)f2bf(a.w);
                wf[4] = (short)f2bf(b.x); wf[5] = (short)f2bf(b.y);
                wf[6] = (short)f2bf(b.z); wf[7] = (short)f2bf(b.w);
            }
            #pragma unroll
            for (int s = 0; s < 2; ++s) {
                f32x4 hd = __builtin_amdgcn_mfma_f32_16x16x32_bf16(
                    zf[s], wf, (f32x4){0.f, 0.f, 0.f, 0.f}, 0, 0, 0);
                // D layout: col = lane&15, row = (lane>>4)*4 + j
                const int row = (wave * 2 + s) * 16 + lhi * 4;
                const int col = ns * 16 + l15;
                #pragma unroll
                for (int j = 0; j < 4; ++j) {
                    const float v = hd[j] > 0.f ? hd[j] : 0.f;
                    hA[(row + j) * HA_ST + col] = f2bf(v);
                }
            }
        }

        __syncthreads();   // hA, Bt ready

        // ---- Main GEMM: acc += h_tile @ W2_tileT ----
        #pragma unroll
        for (int ksub = 0; ksub < 2; ++ksub) {
            bf16x8 af[4], bg[4];
            #pragma unroll
            for (int mi = 0; mi < 4; ++mi) {
                const int row = wm * 64 + mi * 16 + l15;
                af[mi] = *(const bf16x8*)&hA[row * HA_ST + ksub * 32 + lhi * 8];
            }
            #pragma unroll
            for (int ni = 0; ni < 4; ++ni) {
                const int e = wn * 64 + ni * 16 + l15;
                bg[ni] = *(const bf16x8*)&Bt[e * BT_ST + ksub * 32 + lhi * 8];
            }
            #pragma unroll
            for (int mi = 0; mi < 4; ++mi)
                #pragma unroll
                for (int ni = 0; ni < 4; ++ni)
                    acc[mi][ni] = __builtin_amdgcn_mfma_f32_16x16x32_bf16(
                        af[mi], bg[ni], acc[mi][ni], 0, 0, 0);
        }
    }

    // ---- Epilogue: f32 store. D layout: col = lane&15, row = (lane>>4)*4+j ----
    #pragma unroll
    for (int mi = 0; mi < 4; ++mi) {
        const int rbase = t0 + wm * 64 + mi * 16 + lhi * 4;
        #pragma unroll
        for (int ni = 0; ni < 4; ++ni) {
            const int c = n0 + wn * 64 + ni * 16 + l15;
            #pragma unroll
            for (int j = 0; j < 4; ++j) {
                out[(size_t)(rbase + j) * EDIM + c] = acc[mi][ni][j];
            }
        }
    }
}

extern "C" void kernel_launch(void* const* d_in, const int* in_sizes, int n_in,
                              void* d_out, int out_size, void* d_ws, size_t ws_size,
                              hipStream_t stream) {
    const float* x     = (const float*)d_in[0];
    const float* theta = (const float*)d_in[1];
    const float* W1    = (const float*)d_in[2];
    const float* W2    = (const float*)d_in[3];
    float* out = (float*)d_out;

    dim3 grid(NPANEL * NMBLK);   // 1536 blocks
    dim3 block(256);
    ffq_fused<<<grid, block, 0, stream>>>(x, theta, W1, W2, out);
}

// Round 2
// 232.327 us; speedup vs baseline: 1.9594x; 1.9594x over previous
//
#include <hip/hip_runtime.h>
#include <hip/hip_bf16.h>
#include <math.h>

// Problem constants
#define T_TOK   32768            // B*S tokens
#define EDIM    768
#define FDIM    3072
#define NQ      8

// Main tiling: block tile 128 tok x 128 e, 4 waves (2x2), wave tile 64x64,
// mfma_f32_32x32x16_bf16 everywhere.
#define BM      128
#define BN      128
#define NPANEL  (EDIM / BN)      // 6
#define NMBLK   (T_TOK / BM)     // 256
#define NFT     (FDIM / 32)      // 96 f-tiles (32 f each)
#define NET     (EDIM / 32)      // 24 e-tiles
#define NTT     (T_TOK / 32)     // 1024 token-tiles
#define NKF     (FDIM / 16)      // 192 k-frags (16 f each)

// Workspace layout (bytes): fragment-packed bf16 operands.
//  W2P[kf][et][lane][8]  : main-GEMM B-frags, k-slot permutation baked in
//  W1P[ft][lane][8]      : expansion A-frags (g=1 lanes zero = K pad)
//  ZP [tt][lane][8]      : expansion B-frags (g=1 lanes zero = K pad)
#define W2P_BYTES (NKF * NET * 64 * 8 * 2)   // 4,718,592
#define W1P_BYTES (NFT * 64 * 8 * 2)         // 98,304
#define ZP_BYTES  (NTT * 64 * 8 * 2)         // 1,048,576
#define W1P_OFFU  (W2P_BYTES / 2)            // ushort offsets
#define ZP_OFFU   ((W2P_BYTES + W1P_BYTES) / 2)
#define WS_NEED   ((size_t)(W2P_BYTES + W1P_BYTES + ZP_BYTES))

typedef float f32x16 __attribute__((ext_vector_type(16)));
typedef float f32x4  __attribute__((ext_vector_type(4)));
typedef short bf16x8 __attribute__((ext_vector_type(8)));

union FragU { uint4 u; bf16x8 v; };

// Two f32 -> packed bf16x2 (RNE) in one instruction.
static __device__ __forceinline__ unsigned pack2(float lo, float hi) {
    unsigned r;
    asm("v_cvt_pk_bf16_f32 %0, %1, %2" : "=v"(r) : "v"(lo), "v"(hi));
    return r;
}

// Scalar f32 -> bf16 bits, RNE (for the fallback kernel).
static __device__ __forceinline__ unsigned short f2bf(float f) {
    unsigned int u = __float_as_uint(f);
    unsigned int r = (u + 0x7FFFu + ((u >> 16) & 1u)) >> 16;
    return (unsigned short)r;
}

// ---------------------------------------------------------------------------
// Prologue: pack all operands into fragment order (one launch, 3 regions).
//   blocks [0,1152)    -> W2P  (294912 threads)
//   blocks [1152,1176) -> W1P  (6144 threads)
//   blocks [1176,1432) -> ZP   (65536 threads)
// k-slot permutation for main GEMM: slot (g,j) -> f_local = (j>>2)*8 + g*4 + (j&3)
// ---------------------------------------------------------------------------
__global__ __launch_bounds__(256) void ffq_pack(
    const float* __restrict__ x, const float* __restrict__ theta,
    const float* __restrict__ W1, const float* __restrict__ W2,
    unsigned short* __restrict__ ws)
{
    const int bid = blockIdx.x;
    unsigned short* W2P = ws;
    unsigned short* W1P = ws + W1P_OFFU;
    unsigned short* ZP  = ws + ZP_OFFU;

    if (bid < 1152) {
        const int t = bid * 256 + threadIdx.x;     // (kf*24 + et)*64 + lane
        const int lane = t & 63, fe = t >> 6;
        const int kf = fe / NET, et = fe - kf * NET;
        const int g = lane >> 5, c = lane & 31;
        const int e  = et * 32 + c;
        const int f0 = kf * 16 + g * 4;            // first 4-f run of this lane
        const float4 a = *(const float4*)(W2 + (size_t)e * FDIM + f0);
        const float4 b = *(const float4*)(W2 + (size_t)e * FDIM + f0 + 8);
        FragU u;
        u.u.x = pack2(a.x, a.y); u.u.y = pack2(a.z, a.w);
        u.u.z = pack2(b.x, b.y); u.u.w = pack2(b.z, b.w);
        *(uint4*)(W2P + (size_t)t * 8) = u.u;
    } else if (bid < 1176) {
        const int t = (bid - 1152) * 256 + threadIdx.x;  // ft*64 + lane
        const int lane = t & 63, ft = t >> 6;
        const int g = lane >> 5, c = lane & 31;
        FragU u; u.u = (uint4){0, 0, 0, 0};
        if (g == 0) {   // real q = 0..7; g=1 lanes are the K-pad zeros
            const float4 a = *(const float4*)(W1 + (size_t)(ft * 32 + c) * NQ);
            const float4 b = *(const float4*)(W1 + (size_t)(ft * 32 + c) * NQ + 4);
            u.u.x = pack2(a.x, a.y); u.u.y = pack2(a.z, a.w);
            u.u.z = pack2(b.x, b.y); u.u.w = pack2(b.z, b.w);
        }
        *(uint4*)(W1P + (size_t)t * 8) = u.u;
    } else {
        const int t = (bid - 1176) * 256 + threadIdx.x;  // tt*64 + lane
        const int lane = t & 63, tt = t >> 6;
        const int g = lane >> 5, c = lane & 31;
        FragU u; u.u = (uint4){0, 0, 0, 0};
        if (g == 0) {
            const int token = tt * 32 + c;
            const float4 a = *(const float4*)(x + (size_t)token * EDIM);
            const float4 b = *(const float4*)(x + (size_t)token * EDIM + 4);
            const float z0 = __cosf(a.x) * __cosf(theta[0]);
            const float z1 = __cosf(a.y) * __cosf(theta[1]);
            const float z2 = __cosf(a.z) * __cosf(theta[2]);
            const float z3 = __cosf(a.w) * __cosf(theta[3]);
            const float z4 = __cosf(b.x) * __cosf(theta[4]);
            const float z5 = __cosf(b.y) * __cosf(theta[5]);
            const float z6 = __cosf(b.z) * __cosf(theta[6]);
            const float z7 = __cosf(b.w) * __cosf(theta[7]);
            u.u.x = pack2(z0, z1); u.u.y = pack2(z2, z3);
            u.u.z = pack2(z4, z5); u.u.w = pack2(z6, z7);
        }
        *(uint4*)(ZP + (size_t)t * 8) = u.u;
    }
}

// ---------------------------------------------------------------------------
// Main kernel: LDS-free, barrier-free fused FFN.
// Per f-tile (32 f): 2 expansion MFMAs (h^T = W1 @ Z^T) whose D-regs ARE the
// main A-frags (slot permutation baked into W2P), then 8 main MFMAs.
// ---------------------------------------------------------------------------
__global__ __launch_bounds__(256) void ffq_main(
    const unsigned short* __restrict__ ws, float* __restrict__ out)
{
    const unsigned short* W2P = ws;
    const unsigned short* W1P = ws + W1P_OFFU;
    const unsigned short* ZP  = ws + ZP_OFFU;

    const int tid  = threadIdx.x;
    const int wave = tid >> 6;
    const int lane = tid & 63;
    const int g    = (tid >> 5) & 1;
    const int c    = tid & 31;
    const int wm   = wave >> 1;
    const int wn   = wave & 1;

    // XCD swizzle: 1536 = 8*192 blocks; keep a panel's W2P slice on one XCD's L2.
    const int sw    = (blockIdx.x & 7) * 192 + (blockIdx.x >> 3);
    const int panel = sw >> 8;          // / NMBLK
    const int mblk  = sw & 255;         // % NMBLK

    // Hoisted expansion B-frags (Z): constant over the whole k-loop.
    const int tt0 = mblk * 4 + wm * 2;
    const bf16x8 zb0 = *(const bf16x8*)(ZP + ((size_t)tt0 * 64 + lane) * 8);
    const bf16x8 zb1 = *(const bf16x8*)(ZP + ((size_t)(tt0 + 1) * 64 + lane) * 8);

    const int et0 = panel * 4 + wn * 2;
    const size_t laneoff = (size_t)lane * 8;   // ushort units

    f32x16 acc00 = (f32x16)(0.f), acc01 = (f32x16)(0.f);
    f32x16 acc10 = (f32x16)(0.f), acc11 = (f32x16)(0.f);

#define LOADS(ft, WA, B00, B01, B10, B11)                                          \
    do {                                                                           \
        WA  = *(const bf16x8*)(W1P + (size_t)(ft) * 512 + laneoff);                \
        B00 = *(const bf16x8*)(W2P + (size_t)((2*(ft)  ) * NET + et0    ) * 512 + laneoff); \
        B01 = *(const bf16x8*)(W2P + (size_t)((2*(ft)  ) * NET + et0 + 1) * 512 + laneoff); \
        B10 = *(const bf16x8*)(W2P + (size_t)((2*(ft)+1) * NET + et0    ) * 512 + laneoff); \
        B11 = *(const bf16x8*)(W2P + (size_t)((2*(ft)+1) * NET + et0 + 1) * 512 + laneoff); \
    } while (0)

// af slot j = relu(D reg o+j): regs 0..7 -> k-frag 2ft, regs 8..15 -> 2ft+1.
#define MKAF(d, o) ({                                                    \
        FragU u_;                                                        \
        u_.u.x = pack2(fmaxf((d)[(o)+0], 0.f), fmaxf((d)[(o)+1], 0.f));  \
        u_.u.y = pack2(fmaxf((d)[(o)+2], 0.f), fmaxf((d)[(o)+3], 0.f));  \
        u_.u.z = pack2(fmaxf((d)[(o)+4], 0.f), fmaxf((d)[(o)+5], 0.f));  \
        u_.u.w = pack2(fmaxf((d)[(o)+6], 0.f), fmaxf((d)[(o)+7], 0.f));  \
        u_.v; })

#define STEP(WA, B00, B01, B10, B11)                                               \
    do {                                                                           \
        f32x16 d0 = __builtin_amdgcn_mfma_f32_32x32x16_bf16(WA, zb0, (f32x16)(0.f), 0, 0, 0); \
        bf16x8 a0l = MKAF(d0, 0);                                                  \
        bf16x8 a0h = MKAF(d0, 8);                                                  \
        f32x16 d1 = __builtin_amdgcn_mfma_f32_32x32x16_bf16(WA, zb1, (f32x16)(0.f), 0, 0, 0); \
        bf16x8 a1l = MKAF(d1, 0);                                                  \
        bf16x8 a1h = MKAF(d1, 8);                                                  \
        acc00 = __builtin_amdgcn_mfma_f32_32x32x16_bf16(a0l, B00, acc00, 0, 0, 0); \
        acc01 = __builtin_amdgcn_mfma_f32_32x32x16_bf16(a0l, B01, acc01, 0, 0, 0); \
        acc10 = __builtin_amdgcn_mfma_f32_32x32x16_bf16(a1l, B00, acc10, 0, 0, 0); \
        acc11 = __builtin_amdgcn_mfma_f32_32x32x16_bf16(a1l, B01, acc11, 0, 0, 0); \
        acc00 = __builtin_amdgcn_mfma_f32_32x32x16_bf16(a0h, B10, acc00, 0, 0, 0); \
        acc01 = __builtin_amdgcn_mfma_f32_32x32x16_bf16(a0h, B11, acc01, 0, 0, 0); \
        acc10 = __builtin_amdgcn_mfma_f32_32x32x16_bf16(a1h, B10, acc10, 0, 0, 0); \
        acc11 = __builtin_amdgcn_mfma_f32_32x32x16_bf16(a1h, B11, acc11, 0, 0, 0); \
    } while (0)

    bf16x8 waA, b00A, b01A, b10A, b11A;
    bf16x8 waB, b00B, b01B, b10B, b11B;

    LOADS(0, waA, b00A, b01A, b10A, b11A);
    #pragma unroll 1
    for (int ft = 0; ft < NFT - 2; ft += 2) {
        LOADS(ft + 1, waB, b00B, b01B, b10B, b11B);
        STEP(waA, b00A, b01A, b10A, b11A);
        LOADS(ft + 2, waA, b00A, b01A, b10A, b11A);
        STEP(waB, b00B, b01B, b10B, b11B);
    }
    LOADS(NFT - 1, waB, b00B, b01B, b10B, b11B);
    STEP(waA, b00A, b01A, b10A, b11A);
    STEP(waB, b00B, b01B, b10B, b11B);

    // Epilogue: D layout col = e (c), row(token within 32) = (r&3)+8*(r>>2)+4*g.
    const int tokbase = (mblk * 4 + wm * 2) * 32;
    const int ecol    = (panel * 4 + wn * 2) * 32 + c;
    #pragma unroll
    for (int r = 0; r < 16; ++r) {
        const int row = (r & 3) + 8 * (r >> 2) + 4 * g;
        out[(size_t)(tokbase + row) * EDIM + ecol]           = acc00[r];
        out[(size_t)(tokbase + row) * EDIM + ecol + 32]      = acc01[r];
        out[(size_t)(tokbase + 32 + row) * EDIM + ecol]      = acc10[r];
        out[(size_t)(tokbase + 32 + row) * EDIM + ecol + 32] = acc11[r];
    }
#undef LOADS
#undef MKAF
#undef STEP
}

// ---------------------------------------------------------------------------
// Fallback (round-1 kernel, used only if ws_size < WS_NEED): LDS-staged fused
// FFN with 16x16x32 MFMAs. Known-correct, 455 us.
// ---------------------------------------------------------------------------
#define BK      64
#define NKSTEP  (FDIM / BK)
#define HA_ST   72
#define BT_ST   72

__global__ __launch_bounds__(256) void ffq_fused(
    const float* __restrict__ x, const float* __restrict__ theta,
    const float* __restrict__ W1, const float* __restrict__ W2,
    float* __restrict__ out)
{
    __shared__ __align__(16) unsigned short hA[BM * HA_ST];
    __shared__ __align__(16) unsigned short Bt[BN * BT_ST];

    const int tid  = threadIdx.x;
    const int wave = tid >> 6;
    const int lane = tid & 63;
    const int l15  = lane & 15;
    const int lhi  = lane >> 4;
    const int wm   = wave >> 1;
    const int wn   = wave & 1;

    const int panel = blockIdx.x / NMBLK;
    const int mblk  = blockIdx.x % NMBLK;
    const int t0 = mblk * BM;
    const int n0 = panel * BN;

    bf16x8 zf[2];
    #pragma unroll
    for (int s = 0; s < 2; ++s) {
        bf16x8 z = {0, 0, 0, 0, 0, 0, 0, 0};
        if (lhi == 0) {
            const int tok = t0 + (wave * 2 + s) * 16 + l15;
            const float4* xp = (const float4*)(x + (size_t)tok * EDIM);
            const float4 x0 = xp[0];
            const float4 x1 = xp[1];
            z[0] = (short)f2bf(cosf(x0.x) * cosf(theta[0]));
            z[1] = (short)f2bf(cosf(x0.y) * cosf(theta[1]));
            z[2] = (short)f2bf(cosf(x0.z) * cosf(theta[2]));
            z[3] = (short)f2bf(cosf(x0.w) * cosf(theta[3]));
            z[4] = (short)f2bf(cosf(x1.x) * cosf(theta[4]));
            z[5] = (short)f2bf(cosf(x1.y) * cosf(theta[5]));
            z[6] = (short)f2bf(cosf(x1.z) * cosf(theta[6]));
            z[7] = (short)f2bf(cosf(x1.w) * cosf(theta[7]));
        }
        zf[s] = z;
    }

    f32x4 acc[4][4];
    #pragma unroll
    for (int mi = 0; mi < 4; ++mi)
        #pragma unroll
        for (int ni = 0; ni < 4; ++ni)
            acc[mi][ni] = (f32x4){0.f, 0.f, 0.f, 0.f};

    for (int ks = 0; ks < NKSTEP; ++ks) {
        const int k0 = ks * BK;
        __syncthreads();
        {
            const int e    = tid >> 1;
            const int half = (tid & 1) * 32;
            const float* src = W2 + (size_t)(n0 + e) * FDIM + k0 + half;
            unsigned short* dst = &Bt[e * BT_ST + half];
            #pragma unroll
            for (int i = 0; i < 4; ++i) {
                const float4 a = ((const float4*)src)[2 * i];
                const float4 b = ((const float4*)src)[2 * i + 1];
                bf16x8 v;
                v[0] = (short)f2bf(a.x); v[1] = (short)f2bf(a.y);
                v[2] = (short)f2bf(a.z); v[3] = (short)f2bf(a.w);
                v[4] = (short)f2bf(b.x); v[5] = (short)f2bf(b.y);
                v[6] = (short)f2bf(b.z); v[7] = (short)f2bf(b.w);
                *(bf16x8*)(dst + i * 8) = v;
            }
        }
        #pragma unroll
        for (int ns = 0; ns < 4; ++ns) {
            bf16x8 wf = {0, 0, 0, 0, 0, 0, 0, 0};
            if (lhi == 0) {
                const float* wp = W1 + (size_t)(k0 + ns * 16 + l15) * NQ;
                const float4 a = ((const float4*)wp)[0];
                const float4 b = ((const float4*)wp)[1];
                wf[0] = (short)f2bf(a.x); wf[1] = (short)f2bf(a.y);
                wf[2] = (short)f2bf(a.z); wf[3] = (short)f2bf(a.w);
                wf[4] = (short)f2bf(b.x); wf[5] = (short)f2bf(b.y);
                wf[6] = (short)f2bf(b.z); wf[7] = (short)f2bf(b.w);
            }
            #pragma unroll
            for (int s = 0; s < 2; ++s) {
                f32x4 hd = __builtin_amdgcn_mfma_f32_16x16x32_bf16(
                    zf[s], wf, (f32x4){0.f, 0.f, 0.f, 0.f}, 0, 0, 0);
                const int row = (wave * 2 + s) * 16 + lhi * 4;
                const int col = ns * 16 + l15;
                #pragma unroll
                for (int j = 0; j < 4; ++j) {
                    const float v = hd[j] > 0.f ? hd[j] : 0.f;
                    hA[(row + j) * HA_ST + col] = f2bf(v);
                }
            }
        }
        __syncthreads();
        #pragma unroll
        for (int ksub = 0; ksub < 2; ++ksub) {
            bf16x8 af[4], bg[4];
            #pragma unroll
            for (int mi = 0; mi < 4; ++mi) {
                const int row = wm * 64 + mi * 16 + l15;
                af[mi] = *(const bf16x8*)&hA[row * HA_ST + ksub * 32 + lhi * 8];
            }
            #pragma unroll
            for (int ni = 0; ni < 4; ++ni) {
                const int e = wn * 64 + ni * 16 + l15;
                bg[ni] = *(const bf16x8*)&Bt[e * BT_ST + ksub * 32 + lhi * 8];
            }
            #pragma unroll
            for (int mi = 0; mi < 4; ++mi)
                #pragma unroll
                for (int ni = 0; ni < 4; ++ni)
                    acc[mi][ni] = __builtin_amdgcn_mfma_f32_16x16x32_bf16(
                        af[mi], bg[ni], acc[mi][ni], 0, 0, 0);
        }
    }

    #pragma unroll
    for (int mi = 0; mi < 4; ++mi) {
        const int rbase = t0 + wm * 64 + mi * 16 + lhi * 4;
        #pragma unroll
        for (int ni = 0; ni < 4; ++ni) {
            const int cc = n0 + wn * 64 + ni * 16 + l15;
            #pragma unroll
            for (int j = 0; j < 4; ++j)
                out[(size_t)(rbase + j) * EDIM + cc] = acc[mi][ni][j];
        }
    }
}

extern "C" void kernel_launch(void* const* d_in, const int* in_sizes, int n_in,
                              void* d_out, int out_size, void* d_ws, size_t ws_size,
                              hipStream_t stream) {
    const float* x     = (const float*)d_in[0];
    const float* theta = (const float*)d_in[1];
    const float* W1    = (const float*)d_in[2];
    const float* W2    = (const float*)d_in[3];
    float* out = (float*)d_out;

    if (ws_size >= WS_NEED) {
        ffq_pack<<<dim3(1432), dim3(256), 0, stream>>>(x, theta, W1, W2,
                                                       (unsigned short*)d_ws);
        ffq_main<<<dim3(NPANEL * NMBLK), dim3(256), 0, stream>>>(
            (const unsigned short*)d_ws, out);
    } else {
        ffq_fused<<<dim3(NPANEL * NMBLK), dim3(256), 0, stream>>>(x, theta, W1, W2, out);
    }
}

// Round 3
// 169.368 us; speedup vs baseline: 2.6877x; 1.3717x over previous
//
#include <hip/hip_runtime.h>
#include <hip/hip_bf16.h>
#include <math.h>

// Problem constants
#define T_TOK   32768            // B*S tokens
#define EDIM    768
#define FDIM    3072
#define NQ      8

#define NET     24               // EDIM/32  (e-tiles)
#define NKF     192              // FDIM/16  (k-frags)
#define NFT     96               // FDIM/32  (f-tiles = exp steps)
#define NTT     1024             // T_TOK/32 (token-tiles)

// Main geometry: block 128 tok x 192 e, 4 waves (2 wm x 2 wn), wave 64x96.
#define BMQ     128
#define BNQ     192
#define NPAN    4                // EDIM/BNQ
#define NMB     256              // T_TOK/BMQ

// Workspace layout (bytes): fragment-packed bf16 operands.
//  W2P[et][kf][lane][8] : main B-frags, f-permutation baked in (et-major for
//                         SGPR-base + imm-offset streaming along kf)
//  W1P[ft][lane][8]     : expansion A-frags (g=1 lanes zero = K pad)
//  ZP [tt][lane][8]     : expansion B-frags (g=1 lanes zero = K pad)
#define W2P_BYTES (NKF * NET * 64 * 8 * 2)   // 4,718,592
#define W1P_BYTES (NFT * 64 * 8 * 2)         // 98,304
#define ZP_BYTES  (NTT * 64 * 8 * 2)         // 1,048,576
#define W1P_OFFU  (W2P_BYTES / 2)            // ushort offsets
#define ZP_OFFU   ((W2P_BYTES + W1P_BYTES) / 2)
#define WS_NEED   ((size_t)(W2P_BYTES + W1P_BYTES + ZP_BYTES))

typedef float f32x16 __attribute__((ext_vector_type(16)));
typedef float f32x4  __attribute__((ext_vector_type(4)));
typedef short bf16x8 __attribute__((ext_vector_type(8)));

union FragU { uint4 u; bf16x8 v; };

static __device__ __forceinline__ unsigned pack2(float lo, float hi) {
    unsigned r;
    asm("v_cvt_pk_bf16_f32 %0, %1, %2" : "=v"(r) : "v"(lo), "v"(hi));
    return r;
}

static __device__ __forceinline__ unsigned short f2bf(float f) {
    unsigned int u = __float_as_uint(f);
    unsigned int r = (u + 0x7FFFu + ((u >> 16) & 1u)) >> 16;
    return (unsigned short)r;
}

// ---------------------------------------------------------------------------
// Prologue pack: identical fragment math to round 2 (verified); W2P dst is now
// et-major. blocks [0,1152)->W2P, [1152,1176)->W1P, [1176,1432)->ZP.
// ---------------------------------------------------------------------------
__global__ __launch_bounds__(256) void ffq_pack(
    const float* __restrict__ x, const float* __restrict__ theta,
    const float* __restrict__ W1, const float* __restrict__ W2,
    unsigned short* __restrict__ ws)
{
    const int bid = blockIdx.x;
    unsigned short* W2P = ws;
    unsigned short* W1P = ws + W1P_OFFU;
    unsigned short* ZP  = ws + ZP_OFFU;

    if (bid < 1152) {
        const int t = bid * 256 + threadIdx.x;
        const int lane = t & 63, fe = t >> 6;
        const int kf = fe / NET, et = fe - kf * NET;
        const int g = lane >> 5, c = lane & 31;
        const int e  = et * 32 + c;
        const int f0 = kf * 16 + g * 4;
        const float4 a = *(const float4*)(W2 + (size_t)e * FDIM + f0);
        const float4 b = *(const float4*)(W2 + (size_t)e * FDIM + f0 + 8);
        FragU u;
        u.u.x = pack2(a.x, a.y); u.u.y = pack2(a.z, a.w);
        u.u.z = pack2(b.x, b.y); u.u.w = pack2(b.z, b.w);
        *(uint4*)(W2P + (((size_t)et * NKF + kf) * 64 + lane) * 8) = u.u;
    } else if (bid < 1176) {
        const int t = (bid - 1152) * 256 + threadIdx.x;
        const int lane = t & 63, ft = t >> 6;
        const int g = lane >> 5, c = lane & 31;
        FragU u; u.u = (uint4){0, 0, 0, 0};
        if (g == 0) {
            const float4 a = *(const float4*)(W1 + (size_t)(ft * 32 + c) * NQ);
            const float4 b = *(const float4*)(W1 + (size_t)(ft * 32 + c) * NQ + 4);
            u.u.x = pack2(a.x, a.y); u.u.y = pack2(a.z, a.w);
            u.u.z = pack2(b.x, b.y); u.u.w = pack2(b.z, b.w);
        }
        *(uint4*)(W1P + (size_t)t * 8) = u.u;
    } else {
        const int t = (bid - 1176) * 256 + threadIdx.x;
        const int lane = t & 63, tt = t >> 6;
        const int g = lane >> 5, c = lane & 31;
        FragU u; u.u = (uint4){0, 0, 0, 0};
        if (g == 0) {
            const int token = tt * 32 + c;
            const float4 a = *(const float4*)(x + (size_t)token * EDIM);
            const float4 b = *(const float4*)(x + (size_t)token * EDIM + 4);
            const float z0 = __cosf(a.x) * __cosf(theta[0]);
            const float z1 = __cosf(a.y) * __cosf(theta[1]);
            const float z2 = __cosf(a.z) * __cosf(theta[2]);
            const float z3 = __cosf(a.w) * __cosf(theta[3]);
            const float z4 = __cosf(b.x) * __cosf(theta[4]);
            const float z5 = __cosf(b.y) * __cosf(theta[5]);
            const float z6 = __cosf(b.z) * __cosf(theta[6]);
            const float z7 = __cosf(b.w) * __cosf(theta[7]);
            u.u.x = pack2(z0, z1); u.u.y = pack2(z2, z3);
            u.u.z = pack2(z4, z5); u.u.w = pack2(z6, z7);
        }
        *(uint4*)(ZP + (size_t)t * 8) = u.u;
    }
}

// ---------------------------------------------------------------------------
// Main: LDS-free fused FFN, exp-ahead software pipeline.
// Per ft-body: 2 exp MFMA (next ft) + 12 main MFMA + 48 cvt VALU + 9 loads.
// ---------------------------------------------------------------------------
__global__ __launch_bounds__(256, 2) void ffq_main(
    const unsigned short* __restrict__ ws, float* __restrict__ out)
{
    const unsigned short* W2P = ws;
    const unsigned short* W1P = ws + W1P_OFFU;
    const unsigned short* ZP  = ws + ZP_OFFU;

    const int tid  = threadIdx.x;
    const int wave = tid >> 6;
    const int lane = tid & 63;
    const int g    = lane >> 5;
    const int c    = lane & 31;
    const int wm   = wave >> 1;
    const int wn   = wave & 1;

    // XCD swizzle: 1024 blocks = 8 x 128; same-panel blocks share an XCD's L2.
    const int sw    = (blockIdx.x & 7) * 128 + (blockIdx.x >> 3);
    const int panel = sw >> 8;           // 0..3
    const int mblk  = sw & 255;

    const int tt0 = mblk * 4 + wm * 2;
    const int et0 = panel * 6 + wn * 3;
    const size_t lo8 = (size_t)lane * 8;

    const bf16x8 zb0 = *(const bf16x8*)(ZP + (size_t)tt0 * 512 + lo8);
    const bf16x8 zb1 = *(const bf16x8*)(ZP + (size_t)(tt0 + 1) * 512 + lo8);

    const unsigned short* pB0 = W2P + (size_t)(et0 + 0) * NKF * 512 + lo8;
    const unsigned short* pB1 = W2P + (size_t)(et0 + 1) * NKF * 512 + lo8;
    const unsigned short* pB2 = W2P + (size_t)(et0 + 2) * NKF * 512 + lo8;
    const unsigned short* pW  = W1P + lo8;

    const f32x16 Zc = (f32x16)(0.f);
    f32x16 a00 = Zc, a01 = Zc, a02 = Zc, a10 = Zc, a11 = Zc, a12 = Zc;
    f32x16 d0, d1;
    bf16x8 a0l, a0h, a1l, a1h;
    bf16x8 blA0, blA1, blA2, bhA0, bhA1, bhA2;
    bf16x8 blB0, blB1, blB2, bhB0, bhB1, bhB2;
    bf16x8 wa_a, wa_b;

#define MFMA32(A, B, C) __builtin_amdgcn_mfma_f32_32x32x16_bf16((A), (B), (C), 0, 0, 0)

// aF slot j = relu(D reg o+j): regs 0..7 -> lo kf, 8..15 -> hi kf (verified r2).
#define MKAF(d, o) ({                                                    \
        FragU u_;                                                        \
        u_.u.x = pack2(fmaxf((d)[(o)+0], 0.f), fmaxf((d)[(o)+1], 0.f));  \
        u_.u.y = pack2(fmaxf((d)[(o)+2], 0.f), fmaxf((d)[(o)+3], 0.f));  \
        u_.u.z = pack2(fmaxf((d)[(o)+4], 0.f), fmaxf((d)[(o)+5], 0.f));  \
        u_.u.w = pack2(fmaxf((d)[(o)+6], 0.f), fmaxf((d)[(o)+7], 0.f));  \
        u_.v; })

#define CVT() do { a0l = MKAF(d0, 0); a0h = MKAF(d0, 8);                 \
                   a1l = MKAF(d1, 0); a1h = MKAF(d1, 8); } while (0)

#define MAINLO(B0, B1, B2) do {                                          \
        a00 = MFMA32(a0l, (B0), a00); a01 = MFMA32(a0l, (B1), a01);      \
        a02 = MFMA32(a0l, (B2), a02); a10 = MFMA32(a1l, (B0), a10);      \
        a11 = MFMA32(a1l, (B1), a11); a12 = MFMA32(a1l, (B2), a12); } while (0)

#define MAINHI(B0, B1, B2) do {                                          \
        a00 = MFMA32(a0h, (B0), a00); a01 = MFMA32(a0h, (B1), a01);      \
        a02 = MFMA32(a0h, (B2), a02); a10 = MFMA32(a1h, (B0), a10);      \
        a11 = MFMA32(a1h, (B1), a11); a12 = MFMA32(a1h, (B2), a12); } while (0)

// One ft-body. Consumes BL*/BH* (kf=2ft,2ft+1), refills them (kf=2ft+4,2ft+5),
// runs exp for ft+1 (WAEXP) and cvt at the end. WALOAD prefetches WA(ft+2/3).
#define BODY(WALOAD, WAEXP, BL0, BL1, BL2, BH0, BH1, BH2, QLO, QHI, QW) do {   \
        WALOAD = *(const bf16x8*)(qW + (QW));                                  \
        d0 = MFMA32(WAEXP, zb0, Zc);                                           \
        d1 = MFMA32(WAEXP, zb1, Zc);                                           \
        __builtin_amdgcn_s_setprio(1);                                         \
        MAINLO(BL0, BL1, BL2);                                                 \
        __builtin_amdgcn_s_setprio(0);                                         \
        BL0 = *(const bf16x8*)(qB0 + (QLO));                                   \
        BL1 = *(const bf16x8*)(qB1 + (QLO));                                   \
        BL2 = *(const bf16x8*)(qB2 + (QLO));                                   \
        __builtin_amdgcn_s_setprio(1);                                         \
        MAINHI(BH0, BH1, BH2);                                                 \
        __builtin_amdgcn_s_setprio(0);                                         \
        BH0 = *(const bf16x8*)(qB0 + (QHI));                                   \
        BH1 = *(const bf16x8*)(qB1 + (QHI));                                   \
        BH2 = *(const bf16x8*)(qB2 + (QHI));                                   \
        CVT();                                                                 \
    } while (0)

    // Prologue: frags for kf=0..3, WA(0), WA(1); exp+cvt for ft=0.
    blA0 = *(const bf16x8*)(pB0);           blA1 = *(const bf16x8*)(pB1);
    blA2 = *(const bf16x8*)(pB2);
    bhA0 = *(const bf16x8*)(pB0 + 512);     bhA1 = *(const bf16x8*)(pB1 + 512);
    bhA2 = *(const bf16x8*)(pB2 + 512);
    blB0 = *(const bf16x8*)(pB0 + 1024);    blB1 = *(const bf16x8*)(pB1 + 1024);
    blB2 = *(const bf16x8*)(pB2 + 1024);
    bhB0 = *(const bf16x8*)(pB0 + 1536);    bhB1 = *(const bf16x8*)(pB1 + 1536);
    bhB2 = *(const bf16x8*)(pB2 + 1536);
    {
        const bf16x8 wa0 = *(const bf16x8*)(pW);
        wa_b = *(const bf16x8*)(pW + 512);
        d0 = MFMA32(wa0, zb0, Zc);
        d1 = MFMA32(wa0, zb1, Zc);
        CVT();                               // aF(0)
    }

    const unsigned short* qB0 = pB0 + 2048;  // kf=4
    const unsigned short* qB1 = pB1 + 2048;
    const unsigned short* qB2 = pB2 + 2048;
    const unsigned short* qW  = pW + 1024;   // WA(2)

    #pragma unroll 1
    for (int ft = 0; ft < NFT - 2; ft += 2) {
        BODY(wa_a, wa_b, blA0, blA1, blA2, bhA0, bhA1, bhA2, 0, 512, 0);
        BODY(wa_b, wa_a, blB0, blB1, blB2, bhB0, bhB1, bhB2, 1024, 1536, 512);
        qB0 += 2048; qB1 += 2048; qB2 += 2048; qW += 1024;
    }

    // Tail: ft = 94 (set A, exp for 95), then ft = 95 (set B).
    d0 = MFMA32(wa_b, zb0, Zc);
    d1 = MFMA32(wa_b, zb1, Zc);
    MAINLO(blA0, blA1, blA2);
    MAINHI(bhA0, bhA1, bhA2);
    CVT();
    MAINLO(blB0, blB1, blB2);
    MAINHI(bhB0, bhB1, bhB2);

    // Epilogue: D row(token%32) = (r&3)+8*(r>>2)+4g, col(e%32) = c (verified r2).
#define STORE_ACC(ACC, T, E) do {                                              \
        const size_t rb = (size_t)((tt0 + (T)) * 32 + 4 * g) * EDIM            \
                          + (size_t)(et0 + (E)) * 32 + c;                      \
        _Pragma("unroll")                                                      \
        for (int r = 0; r < 16; ++r)                                           \
            out[rb + (size_t)((r & 3) + 8 * (r >> 2)) * EDIM] = ACC[r];        \
    } while (0)

    STORE_ACC(a00, 0, 0); STORE_ACC(a01, 0, 1); STORE_ACC(a02, 0, 2);
    STORE_ACC(a10, 1, 0); STORE_ACC(a11, 1, 1); STORE_ACC(a12, 1, 2);

#undef MFMA32
#undef MKAF
#undef CVT
#undef MAINLO
#undef MAINHI
#undef BODY
#undef STORE_ACC
}

// ---------------------------------------------------------------------------
// Fallback (round-1 kernel) if ws is too small. Known-correct, 455 us.
// ---------------------------------------------------------------------------
#define BM      128
#define NPANEL  6
#define NMBLK   256
#define BK      64
#define NKSTEP  (FDIM / BK)
#define HA_ST   72
#define BT_ST   72

__global__ __launch_bounds__(256) void ffq_fused(
    const float* __restrict__ x, const float* __restrict__ theta,
    const float* __restrict__ W1, const float* __restrict__ W2,
    float* __restrict__ out)
{
    __shared__ __align__(16) unsigned short hA[BM * HA_ST];
    __shared__ __align__(16) unsigned short Bt[BM * BT_ST];

    const int tid  = threadIdx.x;
    const int wave = tid >> 6;
    const int lane = tid & 63;
    const int l15  = lane & 15;
    const int lhi  = lane >> 4;
    const int wm   = wave >> 1;
    const int wn   = wave & 1;

    const int panel = blockIdx.x / NMBLK;
    const int mblk  = blockIdx.x % NMBLK;
    const int t0 = mblk * BM;
    const int n0 = panel * BM;

    bf16x8 zf[2];
    #pragma unroll
    for (int s = 0; s < 2; ++s) {
        bf16x8 z = {0, 0, 0, 0, 0, 0, 0, 0};
        if (lhi == 0) {
            const int tok = t0 + (wave * 2 + s) * 16 + l15;
            const float4* xp = (const float4*)(x + (size_t)tok * EDIM);
            const float4 x0 = xp[0];
            const float4 x1 = xp[1];
            z[0] = (short)f2bf(cosf(x0.x) * cosf(theta[0]));
            z[1] = (short)f2bf(cosf(x0.y) * cosf(theta[1]));
            z[2] = (short)f2bf(cosf(x0.z) * cosf(theta[2]));
            z[3] = (short)f2bf(cosf(x0.w) * cosf(theta[3]));
            z[4] = (short)f2bf(cosf(x1.x) * cosf(theta[4]));
            z[5] = (short)f2bf(cosf(x1.y) * cosf(theta[5]));
            z[6] = (short)f2bf(cosf(x1.z) * cosf(theta[6]));
            z[7] = (short)f2bf(cosf(x1.w) * cosf(theta[7]));
        }
        zf[s] = z;
    }

    f32x4 acc[4][4];
    #pragma unroll
    for (int mi = 0; mi < 4; ++mi)
        #pragma unroll
        for (int ni = 0; ni < 4; ++ni)
            acc[mi][ni] = (f32x4){0.f, 0.f, 0.f, 0.f};

    for (int ks = 0; ks < NKSTEP; ++ks) {
        const int k0 = ks * BK;
        __syncthreads();
        {
            const int e    = tid >> 1;
            const int half = (tid & 1) * 32;
            const float* src = W2 + (size_t)(n0 + e) * FDIM + k0 + half;
            unsigned short* dst = &Bt[e * BT_ST + half];
            #pragma unroll
            for (int i = 0; i < 4; ++i) {
                const float4 a = ((const float4*)src)[2 * i];
                const float4 b = ((const float4*)src)[2 * i + 1];
                bf16x8 v;
                v[0] = (short)f2bf(a.x); v[1] = (short)f2bf(a.y);
                v[2] = (short)f2bf(a.z); v[3] = (short)f2bf(a.w);
                v[4] = (short)f2bf(b.x); v[5] = (short)f2bf(b.y);
                v[6] = (short)f2bf(b.z); v[7] = (short)f2bf(b.w);
                *(bf16x8*)(dst + i * 8) = v;
            }
        }
        #pragma unroll
        for (int ns = 0; ns < 4; ++ns) {
            bf16x8 wf = {0, 0, 0, 0, 0, 0, 0, 0};
            if (lhi == 0) {
                const float* wp = W1 + (size_t)(k0 + ns * 16 + l15) * NQ;
                const float4 a = ((const float4*)wp)[0];
                const float4 b = ((const float4*)wp)[1];
                wf[0] = (short)f2bf(a.x); wf[1] = (short)f2bf(a.y);
                wf[2] = (short)f2bf(a.z); wf[3] = (short)f2bf(a.w);
                wf[4] = (short)f2bf(b.x); wf[5] = (short)f2bf(b.y);
                wf[6] = (short)f2bf(b.z); wf[7] = (short)f2bf(b.w);
            }
            #pragma unroll
            for (int s = 0; s < 2; ++s) {
                f32x4 hd = __builtin_amdgcn_mfma_f32_16x16x32_bf16(
                    zf[s], wf, (f32x4){0.f, 0.f, 0.f, 0.f}, 0, 0, 0);
                const int row = (wave * 2 + s) * 16 + lhi * 4;
                const int col = ns * 16 + l15;
                #pragma unroll
                for (int j = 0; j < 4; ++j) {
                    const float v = hd[j] > 0.f ? hd[j] : 0.f;
                    hA[(row + j) * HA_ST + col] = f2bf(v);
                }
            }
        }
        __syncthreads();
        #pragma unroll
        for (int ksub = 0; ksub < 2; ++ksub) {
            bf16x8 af[4], bg[4];
            #pragma unroll
            for (int mi = 0; mi < 4; ++mi) {
                const int row = wm * 64 + mi * 16 + l15;
                af[mi] = *(const bf16x8*)&hA[row * HA_ST + ksub * 32 + lhi * 8];
            }
            #pragma unroll
            for (int ni = 0; ni < 4; ++ni) {
                const int e = wn * 64 + ni * 16 + l15;
                bg[ni] = *(const bf16x8*)&Bt[e * BT_ST + ksub * 32 + lhi * 8];
            }
            #pragma unroll
            for (int mi = 0; mi < 4; ++mi)
                #pragma unroll
                for (int ni = 0; ni < 4; ++ni)
                    acc[mi][ni] = __builtin_amdgcn_mfma_f32_16x16x32_bf16(
                        af[mi], bg[ni], acc[mi][ni], 0, 0, 0);
        }
    }

    #pragma unroll
    for (int mi = 0; mi < 4; ++mi) {
        const int rbase = t0 + wm * 64 + mi * 16 + lhi * 4;
        #pragma unroll
        for (int ni = 0; ni < 4; ++ni) {
            const int cc = n0 + wn * 64 + ni * 16 + l15;
            #pragma unroll
            for (int j = 0; j < 4; ++j)
                out[(size_t)(rbase + j) * EDIM + cc] = acc[mi][ni][j];
        }
    }
}

extern "C" void kernel_launch(void* const* d_in, const int* in_sizes, int n_in,
                              void* d_out, int out_size, void* d_ws, size_t ws_size,
                              hipStream_t stream) {
    const float* x     = (const float*)d_in[0];
    const float* theta = (const float*)d_in[1];
    const float* W1    = (const float*)d_in[2];
    const float* W2    = (const float*)d_in[3];
    float* out = (float*)d_out;

    if (ws_size >= WS_NEED) {
        ffq_pack<<<dim3(1432), dim3(256), 0, stream>>>(x, theta, W1, W2,
                                                       (unsigned short*)d_ws);
        ffq_main<<<dim3(NPAN * NMB), dim3(256), 0, stream>>>(
            (const unsigned short*)d_ws, out);
    } else {
        ffq_fused<<<dim3(NPANEL * NMBLK), dim3(256), 0, stream>>>(x, theta, W1, W2, out);
    }
}

// Round 4
// 152.277 us; speedup vs baseline: 2.9894x; 1.1122x over previous
//
#include <hip/hip_runtime.h>
#include <hip/hip_bf16.h>
#include <math.h>

// Problem constants
#define T_TOK   32768            // B*S tokens
#define EDIM    768
#define FDIM    3072
#define NQ      8

#define NET     24               // EDIM/32  (e-tiles)
#define NKF     192              // FDIM/16  (k-frags)
#define NFT     96               // FDIM/32  (f-tiles = exp steps)
#define NTT     1024             // T_TOK/32 (token-tiles)

// Main geometry: wave = 64 tok (2 tt) x 128 e (4 et); block = 4 waves stacked
// in M = 256 tok x 128 e. Grid = 128 mblk x 6 panels = 768 blocks.
#define NMB     128
#define NPAN    6

// Workspace layout (bytes): fragment-packed bf16 operands.
//  W2P[et][kf][lane][8] : main B-frags, f-permutation baked in (et-major ->
//                         uniform base advance along kf + 32-bit lane voffset)
//  W1P[ft][lane][8]     : expansion A-frags (g=1 lanes zero = K pad)
//  ZP [tt][lane][8]     : expansion B-frags (g=1 lanes zero = K pad)
#define W2P_BYTES (NKF * NET * 64 * 8 * 2)   // 4,718,592
#define W1P_BYTES (NFT * 64 * 8 * 2)         // 98,304
#define ZP_BYTES  (NTT * 64 * 8 * 2)         // 1,048,576
#define W1P_OFFU  (W2P_BYTES / 2)            // ushort offsets
#define ZP_OFFU   ((W2P_BYTES + W1P_BYTES) / 2)
#define WS_NEED   ((size_t)(W2P_BYTES + W1P_BYTES + ZP_BYTES))

typedef float f32x16 __attribute__((ext_vector_type(16)));
typedef float f32x4  __attribute__((ext_vector_type(4)));
typedef short bf16x8 __attribute__((ext_vector_type(8)));

union FragU { uint4 u; bf16x8 v; };

static __device__ __forceinline__ unsigned pack2(float lo, float hi) {
    unsigned r;
    asm("v_cvt_pk_bf16_f32 %0, %1, %2" : "=v"(r) : "v"(lo), "v"(hi));
    return r;
}

static __device__ __forceinline__ unsigned short f2bf(float f) {
    unsigned int u = __float_as_uint(f);
    unsigned int r = (u + 0x7FFFu + ((u >> 16) & 1u)) >> 16;
    return (unsigned short)r;
}

// ---------------------------------------------------------------------------
// Prologue pack (unchanged from round 2/3 — layout verified).
// blocks [0,1152)->W2P, [1152,1176)->W1P, [1176,1432)->ZP.
// ---------------------------------------------------------------------------
__global__ __launch_bounds__(256) void ffq_pack(
    const float* __restrict__ x, const float* __restrict__ theta,
    const float* __restrict__ W1, const float* __restrict__ W2,
    unsigned short* __restrict__ ws)
{
    const int bid = blockIdx.x;
    unsigned short* W2P = ws;
    unsigned short* W1P = ws + W1P_OFFU;
    unsigned short* ZP  = ws + ZP_OFFU;

    if (bid < 1152) {
        const int t = bid * 256 + threadIdx.x;
        const int lane = t & 63, fe = t >> 6;
        const int kf = fe / NET, et = fe - kf * NET;
        const int g = lane >> 5, c = lane & 31;
        const int e  = et * 32 + c;
        const int f0 = kf * 16 + g * 4;
        const float4 a = *(const float4*)(W2 + (size_t)e * FDIM + f0);
        const float4 b = *(const float4*)(W2 + (size_t)e * FDIM + f0 + 8);
        FragU u;
        u.u.x = pack2(a.x, a.y); u.u.y = pack2(a.z, a.w);
        u.u.z = pack2(b.x, b.y); u.u.w = pack2(b.z, b.w);
        *(uint4*)(W2P + (((size_t)et * NKF + kf) * 64 + lane) * 8) = u.u;
    } else if (bid < 1176) {
        const int t = (bid - 1152) * 256 + threadIdx.x;
        const int lane = t & 63, ft = t >> 6;
        const int g = lane >> 5, c = lane & 31;
        FragU u; u.u = (uint4){0, 0, 0, 0};
        if (g == 0) {
            const float4 a = *(const float4*)(W1 + (size_t)(ft * 32 + c) * NQ);
            const float4 b = *(const float4*)(W1 + (size_t)(ft * 32 + c) * NQ + 4);
            u.u.x = pack2(a.x, a.y); u.u.y = pack2(a.z, a.w);
            u.u.z = pack2(b.x, b.y); u.u.w = pack2(b.z, b.w);
        }
        *(uint4*)(W1P + (size_t)t * 8) = u.u;
    } else {
        const int t = (bid - 1176) * 256 + threadIdx.x;
        const int lane = t & 63, tt = t >> 6;
        const int g = lane >> 5, c = lane & 31;
        FragU u; u.u = (uint4){0, 0, 0, 0};
        if (g == 0) {
            const int token = tt * 32 + c;
            const float4 a = *(const float4*)(x + (size_t)token * EDIM);
            const float4 b = *(const float4*)(x + (size_t)token * EDIM + 4);
            const float z0 = __cosf(a.x) * __cosf(theta[0]);
            const float z1 = __cosf(a.y) * __cosf(theta[1]);
            const float z2 = __cosf(a.z) * __cosf(theta[2]);
            const float z3 = __cosf(a.w) * __cosf(theta[3]);
            const float z4 = __cosf(b.x) * __cosf(theta[4]);
            const float z5 = __cosf(b.y) * __cosf(theta[5]);
            const float z6 = __cosf(b.z) * __cosf(theta[6]);
            const float z7 = __cosf(b.w) * __cosf(theta[7]);
            u.u.x = pack2(z0, z1); u.u.y = pack2(z2, z3);
            u.u.z = pack2(z4, z5); u.u.w = pack2(z6, z7);
        }
        *(uint4*)(ZP + (size_t)t * 8) = u.u;
    }
}

// ---------------------------------------------------------------------------
// Main: LDS-free fused FFN. Wave = 2 tt x 4 et. Per body (1 ft):
//   2 exp MFMA + 16 main MFMA + 48 cvt VALU + 9 loads, with
//   sched_group_barrier {MFMA,VALU} interleave so one wave feeds both pipes.
// ---------------------------------------------------------------------------
#define SGB(mask, n) __builtin_amdgcn_sched_group_barrier((mask), (n), 0)

__global__ __launch_bounds__(256, 2) void ffq_main(
    const unsigned short* __restrict__ ws, float* __restrict__ out)
{
    const unsigned short* W1Pp = ws + W1P_OFFU;
    const unsigned short* ZP   = ws + ZP_OFFU;

    const int tid  = threadIdx.x;
    const int wave = tid >> 6;
    const int lane = tid & 63;
    const int g    = lane >> 5;
    const int c    = lane & 31;

    // XCD swizzle: 768 = 8 x 96 (bijective).
    const int sw    = (blockIdx.x & 7) * 96 + (blockIdx.x >> 3);
    const int panel = sw / NMB;          // 0..5
    const int mblk  = sw % NMB;          // 0..127

    const int tt0 = mblk * 8 + wave * 2; // wave owns tt0, tt0+1
    const int et0 = panel * 4;           // wave spans et0..et0+3
    const size_t lo8 = (size_t)lane * 8;

    const bf16x8 zb0 = *(const bf16x8*)(ZP + (size_t)tt0 * 512 + lo8);
    const bf16x8 zb1 = *(const bf16x8*)(ZP + (size_t)(tt0 + 1) * 512 + lo8);

    // 32-bit per-lane voffsets into W2P; uniform base advances 2048 B/body.
    const unsigned lane16 = (unsigned)lane * 16u;
    const unsigned vo0 = (unsigned)((et0 + 0) * NKF) * 1024u + lane16;
    const unsigned vo1 = (unsigned)((et0 + 1) * NKF) * 1024u + lane16;
    const unsigned vo2 = (unsigned)((et0 + 2) * NKF) * 1024u + lane16;
    const unsigned vo3 = (unsigned)((et0 + 3) * NKF) * 1024u + lane16;
    const char* Wb = (const char*)ws;    // uniform W2P base (advanced in loop)

    const f32x16 Zc = (f32x16)(0.f);
    f32x16 A00 = Zc, A01 = Zc, A02 = Zc, A03 = Zc;
    f32x16 A10 = Zc, A11 = Zc, A12 = Zc, A13 = Zc;
    f32x16 d0, d1;
    bf16x8 a0l, a0h, a1l, a1h;
    bf16x8 Bl0, Bl1, Bl2, Bl3, Bh0, Bh1, Bh2, Bh3;
    bf16x8 wa;

#define MFMA32(A, B, C) __builtin_amdgcn_mfma_f32_32x32x16_bf16((A), (B), (C), 0, 0, 0)

// aF slot j = relu(D reg o+j): regs 0..7 -> lo kf, 8..15 -> hi kf (verified r2).
#define MKAF(d, o) ({                                                    \
        FragU u_;                                                        \
        u_.u.x = pack2(fmaxf((d)[(o)+0], 0.f), fmaxf((d)[(o)+1], 0.f));  \
        u_.u.y = pack2(fmaxf((d)[(o)+2], 0.f), fmaxf((d)[(o)+3], 0.f));  \
        u_.u.z = pack2(fmaxf((d)[(o)+4], 0.f), fmaxf((d)[(o)+5], 0.f));  \
        u_.u.w = pack2(fmaxf((d)[(o)+6], 0.f), fmaxf((d)[(o)+7], 0.f));  \
        u_.v; })

    // ---- Prologue: B-frags kf-pair 0, wa(0), exp(0), wa(1), cvt(0) ----
    Bl0 = *(const bf16x8*)(Wb + vo0);        Bh0 = *(const bf16x8*)(Wb + vo0 + 1024);
    Bl1 = *(const bf16x8*)(Wb + vo1);        Bh1 = *(const bf16x8*)(Wb + vo1 + 1024);
    Bl2 = *(const bf16x8*)(Wb + vo2);        Bh2 = *(const bf16x8*)(Wb + vo2 + 1024);
    Bl3 = *(const bf16x8*)(Wb + vo3);        Bh3 = *(const bf16x8*)(Wb + vo3 + 1024);
    wa  = *(const bf16x8*)(W1Pp + lo8);
    d0 = MFMA32(wa, zb0, Zc);
    d1 = MFMA32(wa, zb1, Zc);
    wa  = *(const bf16x8*)(W1Pp + 512 + lo8);
    a0l = MKAF(d0, 0); a0h = MKAF(d0, 8);
    a1l = MKAF(d1, 0); a1h = MKAF(d1, 8);

    #pragma unroll 1
    for (int n = 0; n < NFT; ++n) {
        // exp for ft n+1 (operands read at issue; wa then reloads for n+2)
        d0 = MFMA32(wa, zb0, Zc);
        d1 = MFMA32(wa, zb1, Zc);
        wa = *(const bf16x8*)(W1Pp + (size_t)(n + 2) * 512 + lo8);

        // lo phase: 8 mains on kf-lo, then refill Bl (kf-pair n+1), cvt-lo
        A00 = MFMA32(a0l, Bl0, A00); A01 = MFMA32(a0l, Bl1, A01);
        A02 = MFMA32(a0l, Bl2, A02); A03 = MFMA32(a0l, Bl3, A03);
        A10 = MFMA32(a1l, Bl0, A10); A11 = MFMA32(a1l, Bl1, A11);
        A12 = MFMA32(a1l, Bl2, A12); A13 = MFMA32(a1l, Bl3, A13);
        Bl0 = *(const bf16x8*)(Wb + vo0 + 2048);
        Bl1 = *(const bf16x8*)(Wb + vo1 + 2048);
        Bl2 = *(const bf16x8*)(Wb + vo2 + 2048);
        Bl3 = *(const bf16x8*)(Wb + vo3 + 2048);
        a0l = MKAF(d0, 0);
        a1l = MKAF(d1, 0);
        // schedule: exp(2) + 4x{main 2, cvt 6} over the lo region
        SGB(0x8, 2);
        SGB(0x8, 2); SGB(0x2, 6);
        SGB(0x8, 2); SGB(0x2, 6);
        SGB(0x8, 2); SGB(0x2, 6);
        SGB(0x8, 2); SGB(0x2, 6);

        // hi phase: 8 mains on kf-hi, refill Bh, cvt-hi
        A00 = MFMA32(a0h, Bh0, A00); A01 = MFMA32(a0h, Bh1, A01);
        A02 = MFMA32(a0h, Bh2, A02); A03 = MFMA32(a0h, Bh3, A03);
        A10 = MFMA32(a1h, Bh0, A10); A11 = MFMA32(a1h, Bh1, A11);
        A12 = MFMA32(a1h, Bh2, A12); A13 = MFMA32(a1h, Bh3, A13);
        Bh0 = *(const bf16x8*)(Wb + vo0 + 3072);
        Bh1 = *(const bf16x8*)(Wb + vo1 + 3072);
        Bh2 = *(const bf16x8*)(Wb + vo2 + 3072);
        Bh3 = *(const bf16x8*)(Wb + vo3 + 3072);
        a0h = MKAF(d0, 8);
        a1h = MKAF(d1, 8);
        SGB(0x8, 2); SGB(0x2, 6);
        SGB(0x8, 2); SGB(0x2, 6);
        SGB(0x8, 2); SGB(0x2, 6);
        SGB(0x8, 2); SGB(0x2, 6);

        Wb += 2048;
    }

    // ---- Epilogue: D row(token%32) = (r&3)+8*(r>>2)+4g, col(e%32) = c ----
#define STORE_ACC(ACC, T, E) do {                                              \
        const size_t rb = (size_t)((tt0 + (T)) * 32 + 4 * g) * EDIM            \
                          + (size_t)(et0 + (E)) * 32 + c;                      \
        _Pragma("unroll")                                                      \
        for (int r = 0; r < 16; ++r)                                           \
            out[rb + (size_t)((r & 3) + 8 * (r >> 2)) * EDIM] = ACC[r];        \
    } while (0)

    STORE_ACC(A00, 0, 0); STORE_ACC(A01, 0, 1); STORE_ACC(A02, 0, 2); STORE_ACC(A03, 0, 3);
    STORE_ACC(A10, 1, 0); STORE_ACC(A11, 1, 1); STORE_ACC(A12, 1, 2); STORE_ACC(A13, 1, 3);

#undef MFMA32
#undef MKAF
#undef STORE_ACC
}

// ---------------------------------------------------------------------------
// Fallback (round-1 kernel) if ws is too small. Known-correct, 455 us.
// ---------------------------------------------------------------------------
#define BM      128
#define NPANEL  6
#define NMBLK   256
#define BK      64
#define NKSTEP  (FDIM / BK)
#define HA_ST   72
#define BT_ST   72

__global__ __launch_bounds__(256) void ffq_fused(
    const float* __restrict__ x, const float* __restrict__ theta,
    const float* __restrict__ W1, const float* __restrict__ W2,
    float* __restrict__ out)
{
    __shared__ __align__(16) unsigned short hA[BM * HA_ST];
    __shared__ __align__(16) unsigned short Bt[BM * BT_ST];

    const int tid  = threadIdx.x;
    const int wave = tid >> 6;
    const int lane = tid & 63;
    const int l15  = lane & 15;
    const int lhi  = lane >> 4;
    const int wm   = wave >> 1;
    const int wn   = wave & 1;

    const int panel = blockIdx.x / NMBLK;
    const int mblk  = blockIdx.x % NMBLK;
    const int t0 = mblk * BM;
    const int n0 = panel * BM;

    bf16x8 zf[2];
    #pragma unroll
    for (int s = 0; s < 2; ++s) {
        bf16x8 z = {0, 0, 0, 0, 0, 0, 0, 0};
        if (lhi == 0) {
            const int tok = t0 + (wave * 2 + s) * 16 + l15;
            const float4* xp = (const float4*)(x + (size_t)tok * EDIM);
            const float4 x0 = xp[0];
            const float4 x1 = xp[1];
            z[0] = (short)f2bf(cosf(x0.x) * cosf(theta[0]));
            z[1] = (short)f2bf(cosf(x0.y) * cosf(theta[1]));
            z[2] = (short)f2bf(cosf(x0.z) * cosf(theta[2]));
            z[3] = (short)f2bf(cosf(x0.w) * cosf(theta[3]));
            z[4] = (short)f2bf(cosf(x1.x) * cosf(theta[4]));
            z[5] = (short)f2bf(cosf(x1.y) * cosf(theta[5]));
            z[6] = (short)f2bf(cosf(x1.z) * cosf(theta[6]));
            z[7] = (short)f2bf(cosf(x1.w) * cosf(theta[7]));
        }
        zf[s] = z;
    }

    f32x4 acc[4][4];
    #pragma unroll
    for (int mi = 0; mi < 4; ++mi)
        #pragma unroll
        for (int ni = 0; ni < 4; ++ni)
            acc[mi][ni] = (f32x4){0.f, 0.f, 0.f, 0.f};

    for (int ks = 0; ks < NKSTEP; ++ks) {
        const int k0 = ks * BK;
        __syncthreads();
        {
            const int e    = tid >> 1;
            const int half = (tid & 1) * 32;
            const float* src = W2 + (size_t)(n0 + e) * FDIM + k0 + half;
            unsigned short* dst = &Bt[e * BT_ST + half];
            #pragma unroll
            for (int i = 0; i < 4; ++i) {
                const float4 a = ((const float4*)src)[2 * i];
                const float4 b = ((const float4*)src)[2 * i + 1];
                bf16x8 v;
                v[0] = (short)f2bf(a.x); v[1] = (short)f2bf(a.y);
                v[2] = (short)f2bf(a.z); v[3] = (short)f2bf(a.w);
                v[4] = (short)f2bf(b.x); v[5] = (short)f2bf(b.y);
                v[6] = (short)f2bf(b.z); v[7] = (short)f2bf(b.w);
                *(bf16x8*)(dst + i * 8) = v;
            }
        }
        #pragma unroll
        for (int ns = 0; ns < 4; ++ns) {
            bf16x8 wf = {0, 0, 0, 0, 0, 0, 0, 0};
            if (lhi == 0) {
                const float* wp = W1 + (size_t)(k0 + ns * 16 + l15) * NQ;
                const float4 a = ((const float4*)wp)[0];
                const float4 b = ((const float4*)wp)[1];
                wf[0] = (short)f2bf(a.x); wf[1] = (short)f2bf(a.y);
                wf[2] = (short)f2bf(a.z); wf[3] = (short)f2bf(a.w);
                wf[4] = (short)f2bf(b.x); wf[5] = (short)f2bf(b.y);
                wf[6] = (short)f2bf(b.z); wf[7] = (short)f2bf(b.w);
            }
            #pragma unroll
            for (int s = 0; s < 2; ++s) {
                f32x4 hd = __builtin_amdgcn_mfma_f32_16x16x32_bf16(
                    zf[s], wf, (f32x4){0.f, 0.f, 0.f, 0.f}, 0, 0, 0);
                const int row = (wave * 2 + s) * 16 + lhi * 4;
                const int col = ns * 16 + l15;
                #pragma unroll
                for (int j = 0; j < 4; ++j) {
                    const float v = hd[j] > 0.f ? hd[j] : 0.f;
                    hA[(row + j) * HA_ST + col] = f2bf(v);
                }
            }
        }
        __syncthreads();
        #pragma unroll
        for (int ksub = 0; ksub < 2; ++ksub) {
            bf16x8 af[4], bg[4];
            #pragma unroll
            for (int mi = 0; mi < 4; ++mi) {
                const int row = wm * 64 + mi * 16 + l15;
                af[mi] = *(const bf16x8*)&hA[row * HA_ST + ksub * 32 + lhi * 8];
            }
            #pragma unroll
            for (int ni = 0; ni < 4; ++ni) {
                const int e = wn * 64 + ni * 16 + l15;
                bg[ni] = *(const bf16x8*)&Bt[e * BT_ST + ksub * 32 + lhi * 8];
            }
            #pragma unroll
            for (int mi = 0; mi < 4; ++mi)
                #pragma unroll
                for (int ni = 0; ni < 4; ++ni)
                    acc[mi][ni] = __builtin_amdgcn_mfma_f32_16x16x32_bf16(
                        af[mi], bg[ni], acc[mi][ni], 0, 0, 0);
        }
    }

    #pragma unroll
    for (int mi = 0; mi < 4; ++mi) {
        const int rbase = t0 + wm * 64 + mi * 16 + lhi * 4;
        #pragma unroll
        for (int ni = 0; ni < 4; ++ni) {
            const int cc = n0 + wn * 64 + ni * 16 + l15;
            #pragma unroll
            for (int j = 0; j < 4; ++j)
                out[(size_t)(rbase + j) * EDIM + cc] = acc[mi][ni][j];
        }
    }
}

extern "C" void kernel_launch(void* const* d_in, const int* in_sizes, int n_in,
                              void* d_out, int out_size, void* d_ws, size_t ws_size,
                              hipStream_t stream) {
    const float* x     = (const float*)d_in[0];
    const float* theta = (const float*)d_in[1];
    const float* W1    = (const float*)d_in[2];
    const float* W2    = (const float*)d_in[3];
    float* out = (float*)d_out;

    if (ws_size >= WS_NEED) {
        ffq_pack<<<dim3(1432), dim3(256), 0, stream>>>(x, theta, W1, W2,
                                                       (unsigned short*)d_ws);
        ffq_main<<<dim3(NPAN * NMB), dim3(256), 0, stream>>>(
            (const unsigned short*)d_ws, out);
    } else {
        ffq_fused<<<dim3(NPANEL * NMBLK), dim3(256), 0, stream>>>(x, theta, W1, W2, out);
    }
}